// Round 4
// baseline (220.622 us; speedup 1.0000x reference)
//
#include <hip/hip_runtime.h>

typedef __bf16 bf16x8 __attribute__((ext_vector_type(8)));
typedef float f32x4 __attribute__((ext_vector_type(4)));

#define B_ 16
#define T_ 1024
#define D_ 512
#define S_ 12
#define C_ 11
static constexpr int P_TOTAL = 2148960;  // 176 * (12*1024 - 78)

__device__ __host__ inline constexpr int pred_base(int i) {
  return C_ * B_ * (T_ * i - (i * (i + 1)) / 2);
}

__device__ inline unsigned short f2bf(float f) {
  unsigned int u = __float_as_uint(f);
  u += 0x7FFF + ((u >> 16) & 1);   // round-to-nearest-even
  return (unsigned short)(u >> 16);
}

__device__ inline void gld16(const void* g, void* l) {
  __builtin_amdgcn_global_load_lds(
      (const __attribute__((address_space(1))) void*)g,
      (__attribute__((address_space(3))) void*)l, 16, 0, 0);
}

// ---------------- prep: W [i][o][s] f32 -> wt [s][o][i] bf16 ----------------
__global__ __launch_bounds__(256) void prep_w(const float* __restrict__ W,
                                              unsigned short* __restrict__ wt) {
  __shared__ unsigned short tile[32][33][12];
  const int i0 = blockIdx.x * 32, o0 = blockIdx.y * 32;
#pragma unroll
  for (int q = 0; q < 48; ++q) {
    int idx = threadIdx.x + q * 256;
    int ii = idx / 384, rem = idx % 384;
    tile[ii][rem / 12][rem % 12] =
        f2bf(W[(size_t)(i0 + ii) * 6144 + (size_t)o0 * 12 + rem]);
  }
  __syncthreads();
#pragma unroll
  for (int q = 0; q < 48; ++q) {
    int idx = threadIdx.x + q * 256;
    int ss = idx / 1024, rem = idx % 1024;
    int oo = rem / 32, ii = rem % 32;
    wt[(size_t)ss * (D_ * D_) + (size_t)(o0 + oo) * D_ + (i0 + ii)] = tile[ii][oo][ss];
  }
}

// -- prep: transpose [b][D][T] f32 -> [b][T][D] bf16, both x and y (z=0..31) --
__global__ __launch_bounds__(256) void prep_t2(const float* __restrict__ xin,
                                               const float* __restrict__ yin,
                                               unsigned short* __restrict__ xo,
                                               unsigned short* __restrict__ yo) {
  __shared__ float tile[32][33];
  const int t0 = blockIdx.x * 32;
  const int d0 = blockIdx.y * 32;
  const int b = blockIdx.z & 15;
  const float* in = (blockIdx.z < 16) ? xin : yin;
  unsigned short* ob = (blockIdx.z < 16) ? xo : yo;
  const float* ib = in + (size_t)b * D_ * T_;
  const int r = threadIdx.x / 32, c = threadIdx.x % 32;
#pragma unroll
  for (int p = 0; p < 4; ++p) {
    int rr = r + p * 8;
    tile[rr][c] = ib[(size_t)(d0 + rr) * T_ + t0 + c];
  }
  __syncthreads();
  unsigned short* op = ob + (size_t)b * T_ * D_;
#pragma unroll
  for (int p = 0; p < 4; ++p) {
    int rr = r + p * 8;
    op[(size_t)(t0 + rr) * D_ + d0 + c] = f2bf(tile[c][rr]);
  }
}

// ---------------- labels ----------------
__global__ void labels_k(float* __restrict__ lab) {
  int k = blockIdx.x * 256 + threadIdx.x;
  if (k >= P_TOTAL) return;
  int i = 0;
#pragma unroll
  for (int q = 1; q < 12; ++q)
    if (k >= pred_base(q)) i = q;
  int rel = k - pred_base(i);
  int len = T_ - 1 - i;
  lab[k] = (rel < B_ * len) ? 1.0f : 0.0f;
}

// ---- GEMM: xp[bl][s][t][o] = xb[m][i] * wt[s][o][i] + bias[o] --------------
// Persistent blocks, 256x256 tile, BK=32, 8 waves, ring-4 LDS (128 KiB).
// Fully-unrolled K-loop with cross-phase frag preloads: every ds_read burst
// overlaps an MFMA cluster (compiler emits counted lgkmcnt per-register).
// One barrier + one counted vmcnt(4) per K-tile; staging is continuous
// across tile boundaries (ring slot = absolute K-index & 3).
__global__ __launch_bounds__(512, 2) void gemm_xp(
    const unsigned short* __restrict__ xb,   // [bc*1024][512]
    const unsigned short* __restrict__ wt,   // [12][512 o][512 i]
    const float* __restrict__ bias,          // [512]
    unsigned short* __restrict__ xp,         // [bc][12][1024][512]
    int tiles, int mtiles) {
  __shared__ unsigned short lds[65536];      // 4 slots x (A 8192 + B 8192) shorts
  const int tid = threadIdx.x;
  const int w = tid >> 6, l = tid & 63;
  const int gm = w >> 2, gn = w & 3;         // wave tile: 128m x 64n
  const int fr = l & 15, sgrp = l >> 4;

  // staging: 2 x gld16 per 16KB operand tile; source column pre-swizzled
  // (rule #21: LDS dest linear, inverse swizzle on global source).
  const int so0 = tid * 16;
  const int row0 = so0 >> 6, sc0 = (so0 >> 4) & 3;
  const int go0 = row0 * 1024 + ((sc0 ^ ((row0 >> 1) & 3)) << 4);
  const int so1 = so0 + 8192;
  const int row1 = so1 >> 6, sc1 = (so1 >> 4) & 3;
  const int go1 = row1 * 1024 + ((sc1 ^ ((row1 >> 1) & 3)) << 4);

  auto stage = [&](const unsigned short* srcKt, int slotShorts) {
    gld16((const char*)srcKt + go0, (char*)&lds[slotShorts] + so0);
    gld16((const char*)srcKt + go1, (char*)&lds[slotShorts] + so1);
  };

  // invariant swizzled frag offsets (shorts, within a slot)
  int aOff[2][4], bOff[4];
#pragma unroll
  for (int ms = 0; ms < 2; ++ms)
#pragma unroll
    for (int fm = 0; fm < 4; ++fm) {
      int row = gm * 128 + ms * 64 + fm * 16 + fr;
      aOff[ms][fm] = row * 32 + ((sgrp ^ ((row >> 1) & 3)) << 3);
    }
#pragma unroll
  for (int fn = 0; fn < 4; ++fn) {
    int row = gn * 64 + fn * 16 + fr;
    bOff[fn] = row * 32 + ((sgrp ^ ((row >> 1) & 3)) << 3);
  }

  auto decode = [&](int t, const unsigned short*& Ag, const unsigned short*& Bg,
                    int& n0v, int& miv, int& siv) {
    miv = t % mtiles;
    int rest = t / mtiles;
    int ni = rest & 1;
    siv = rest >> 1;
    Ag = xb + (size_t)(miv * 256) * D_;
    Bg = wt + ((size_t)siv * D_ + ni * 256) * D_;
    n0v = ni * 256;
  };

  int ti = blockIdx.x;
  if (ti >= tiles) return;
  const unsigned short *Ag, *Bg, *Agn = nullptr, *Bgn = nullptr;
  int n0, mi, si, n0n, min_, sin_;
  decode(ti, Ag, Bg, n0, mi, si);
  int tin = ti + gridDim.x;
  bool hasNext = tin < tiles;
  if (hasNext) decode(tin, Agn, Bgn, n0n, min_, sin_);

  // prologue: K-tiles 0,1
  stage(Ag, 0);
  stage(Bg, 8192);
  stage(Ag + 32, 16384);
  stage(Bg + 32, 16384 + 8192);
  asm volatile("s_waitcnt vmcnt(4)" ::: "memory");
  __builtin_amdgcn_s_barrier();

  // preload kt=0 ms0 fragments
  bf16x8 afA[4], bfrA[4];
#pragma unroll
  for (int fn = 0; fn < 4; ++fn)
    bfrA[fn] = *(const bf16x8*)&lds[8192 + bOff[fn]];
#pragma unroll
  for (int fm = 0; fm < 4; ++fm)
    afA[fm] = *(const bf16x8*)&lds[aOff[0][fm]];

  while (true) {
    f32x4 acc[2][4][4];
#pragma unroll
    for (int ms = 0; ms < 2; ++ms)
#pragma unroll
      for (int fm = 0; fm < 4; ++fm)
#pragma unroll
        for (int fn = 0; fn < 4; ++fn)
#pragma unroll
          for (int e = 0; e < 4; ++e) acc[ms][fm][fn][e] = 0.f;

    float bv[4];
#pragma unroll
    for (int fn = 0; fn < 4; ++fn) bv[fn] = bias[n0 + gn * 64 + fn * 16 + fr];

#pragma unroll
    for (int kt = 0; kt < 16; ++kt) {
      const int sl = (kt & 3) * 16384;
      // 1) preload ms1 A-frags of current K-tile (overlaps MFMA ms0 below)
      bf16x8 afB[4];
#pragma unroll
      for (int fm = 0; fm < 4; ++fm)
        afB[fm] = *(const bf16x8*)&lds[sl + aOff[1][fm]];

      // 2) stage K-tile kt+2 (ring slot (kt+2)&3 — never in use)
      const int k2 = kt + 2;
      const int sl2 = (k2 & 3) * 16384;
      bool st = false;
      if (k2 < 16) {
        stage(Ag + k2 * 32, sl2);
        stage(Bg + k2 * 32, sl2 + 8192);
        st = true;
      } else if (hasNext) {
        stage(Agn + (k2 - 16) * 32, sl2);
        stage(Bgn + (k2 - 16) * 32, sl2 + 8192);
        st = true;
      }

      // 3) MFMA cluster ms0
      __builtin_amdgcn_s_setprio(1);
#pragma unroll
      for (int fm = 0; fm < 4; ++fm)
#pragma unroll
        for (int fn = 0; fn < 4; ++fn)
          acc[0][fm][fn] = __builtin_amdgcn_mfma_f32_16x16x32_bf16(
              afA[fm], bfrA[fn], acc[0][fm][fn], 0, 0, 0);
      __builtin_amdgcn_s_setprio(0);

      // 4) counted wait for K-tile kt+1's 4 loads, then barrier
      if (st) {
        asm volatile("s_waitcnt vmcnt(4)" ::: "memory");
      } else if (kt == 14) {
        asm volatile("s_waitcnt vmcnt(0)" ::: "memory");
      }
      __builtin_amdgcn_s_barrier();

      // 5) preload next K-step's ms0 frags (overlaps MFMA ms1 below)
      bf16x8 afN[4], bfN[4];
      const bool pre = (kt < 15) || hasNext;
      if (pre) {
        const int nsl = ((kt + 1) & 3) * 16384;
#pragma unroll
        for (int fn = 0; fn < 4; ++fn)
          bfN[fn] = *(const bf16x8*)&lds[nsl + 8192 + bOff[fn]];
#pragma unroll
        for (int fm = 0; fm < 4; ++fm)
          afN[fm] = *(const bf16x8*)&lds[nsl + aOff[0][fm]];
      }

      // 6) MFMA cluster ms1 (uses afB + current bfrA)
      __builtin_amdgcn_s_setprio(1);
#pragma unroll
      for (int fm = 0; fm < 4; ++fm)
#pragma unroll
        for (int fn = 0; fn < 4; ++fn)
          acc[1][fm][fn] = __builtin_amdgcn_mfma_f32_16x16x32_bf16(
              afB[fm], bfrA[fn], acc[1][fm][fn], 0, 0, 0);
      __builtin_amdgcn_s_setprio(0);

      // 7) commit pipeline regs (pure renaming after full unroll)
      if (pre) {
#pragma unroll
        for (int fm = 0; fm < 4; ++fm) afA[fm] = afN[fm];
#pragma unroll
        for (int fn = 0; fn < 4; ++fn) bfrA[fn] = bfN[fn];
      }
    }

    // epilogue: bias + bf16 store (overlaps next tile's in-flight stages)
#pragma unroll
    for (int ms = 0; ms < 2; ++ms) {
#pragma unroll
      for (int fm = 0; fm < 4; ++fm) {
#pragma unroll
        for (int r = 0; r < 4; ++r) {
          int m = mi * 256 + gm * 128 + ms * 64 + fm * 16 + sgrp * 4 + r;
          int bl = m >> 10, t = m & 1023;
          size_t orow = (((size_t)bl * S_ + si) * T_ + t) * D_;
#pragma unroll
          for (int fn = 0; fn < 4; ++fn) {
            int o = n0 + gn * 64 + fn * 16 + fr;
            xp[orow + o] = f2bf(acc[ms][fm][fn][r] + bv[fn]);
          }
        }
      }
    }

    if (!hasNext) break;
    ti = tin;
    Ag = Agn; Bg = Bgn; n0 = n0n; mi = min_; si = sin_;
    tin = ti + gridDim.x;
    hasNext = tin < tiles;
    if (hasNext) decode(tin, Agn, Bgn, n0n, min_, sin_);
  }
}

// ---- predictions: one wave per (b, 4 x tt); 12x11 tiles via 16 MFMAs each --
__global__ __launch_bounds__(256) void pred_k(
    const unsigned short* __restrict__ xp,   // [bc][12][1024][512]
    const unsigned short* __restrict__ yT,   // [16][1024][512]
    const int* __restrict__ negs,            // [16][10][1024]
    float* __restrict__ preds, int b0) {
  const int w = threadIdx.x >> 6, l = threadIdx.x & 63;
  const int bl = blockIdx.y;
  const int b = b0 + bl;
  const int fr = l & 15;
  const int koff = (l >> 4) * 8;

  const unsigned short* arow[4];
  const unsigned short* brow[4];
  int tts[4];
#pragma unroll
  for (int q = 0; q < 4; ++q) {
    int tt = blockIdx.x * 4 + w + q * 256;
    tts[q] = tt;
    int t = tt - 1 - fr;
    bool av = (fr < S_) && (t >= 0);
    arow[q] = xp + (((size_t)bl * S_ + (av ? fr : 0)) * T_ + (av ? t : 0)) * D_;
    int j = tt;
    if (fr >= 1 && fr <= 10) j = negs[b * (10 * T_) + (fr - 1) * T_ + tt];
    brow[q] = yT + ((size_t)b * T_ + j) * D_;
  }

  f32x4 acc[4];
#pragma unroll
  for (int q = 0; q < 4; ++q)
#pragma unroll
    for (int e = 0; e < 4; ++e) acc[q][e] = 0.f;

#pragma unroll
  for (int kk = 0; kk < 16; ++kk) {
#pragma unroll
    for (int q = 0; q < 4; ++q) {
      bf16x8 a = *(const bf16x8*)(arow[q] + kk * 32 + koff);
      bf16x8 bb = *(const bf16x8*)(brow[q] + kk * 32 + koff);
      acc[q] = __builtin_amdgcn_mfma_f32_16x16x32_bf16(a, bb, acc[q], 0, 0, 0);
    }
  }

#pragma unroll
  for (int q = 0; q < 4; ++q) {
#pragma unroll
    for (int r = 0; r < 4; ++r) {
      int ii = (l >> 4) * 4 + r;
      int to = tts[q] - 1 - ii;
      if (ii < S_ && fr < C_ && tts[q] >= 1 && to >= 0) {
        int len = T_ - 1 - ii;
        preds[pred_base(ii) + ((size_t)fr * B_ + b) * len + to] = acc[q][r];
      }
    }
  }
}

extern "C" void kernel_launch(void* const* d_in, const int* in_sizes, int n_in,
                              void* d_out, int out_size, void* d_ws, size_t ws_size,
                              hipStream_t stream) {
  (void)in_sizes; (void)n_in; (void)out_size;
  const float* x = (const float*)d_in[0];
  const float* y = (const float*)d_in[1];
  const float* W = (const float*)d_in[2];
  const float* bias = (const float*)d_in[3];
  const int* negs = (const int*)d_in[4];
  float* out = (float*)d_out;
  char* ws = (char*)d_ws;

  unsigned short* wt = (unsigned short*)ws;                         // 6,291,456 B
  unsigned short* xb = (unsigned short*)(ws + 6291456);             // 16,777,216 B
  unsigned short* yT = (unsigned short*)(ws + 6291456 + 16777216);  // 16,777,216 B
  unsigned short* xp = (unsigned short*)(ws + 6291456 + 2 * 16777216);
  const size_t fixed = 6291456 + (size_t)2 * 16777216;              // 39,845,888
  const size_t xp_per_b = (size_t)S_ * T_ * D_ * 2;                 // 12,582,912
  int nb = 1;
  if (ws_size > fixed) {
    size_t cap = (ws_size - fixed) / xp_per_b;
    nb = cap < 1 ? 1 : (cap > 16 ? 16 : (int)cap);
  }

  hipLaunchKernelGGL(prep_w, dim3(16, 16), dim3(256), 0, stream, W, wt);
  hipLaunchKernelGGL(prep_t2, dim3(32, 16, 32), dim3(256), 0, stream, x, y, xb, yT);
  hipLaunchKernelGGL(labels_k, dim3((P_TOTAL + 255) / 256), dim3(256), 0, stream,
                     out + P_TOTAL);

  for (int b0 = 0; b0 < B_; b0 += nb) {
    int bc = (B_ - b0) < nb ? (B_ - b0) : nb;
    int tiles = bc * 4 * 2 * 12;
    int grid = tiles < 256 ? tiles : 256;
    hipLaunchKernelGGL(gemm_xp, dim3(grid), dim3(512), 0, stream,
                       xb + (size_t)b0 * T_ * D_, wt, bias, xp,
                       tiles, bc * 4);
    hipLaunchKernelGGL(pred_k, dim3(64, bc), dim3(256), 0, stream,
                       xp, yT, negs, out, b0);
  }
}